// Round 16
// baseline (109.952 us; speedup 1.0000x reference)
//
#include <hip/hip_runtime.h>
#include <math.h>
#include <stdint.h>

#define TPB 256
constexpr int Bn = 64;
constexpr int Ln = 262144;          // 2^18
constexpr int S  = 2048;            // chunk/tile size
constexpr int NC = Ln / S;          // 128 chunks per row
constexpr int HA = S + 301;         // halo'd extent (2349)
constexpr int EPT = 12;             // elements per thread (16B-aligned segments)
constexpr int NF4 = 641;            // float4s DMA'd per array (raw slots [0,2564))
constexpr int LDSZ = 3076;          // raw slots reach 3072; prefix reach 3071
constexpr int NW = TPB / 64;

constexpr float TWO_PI_F = 6.28318530717958647692f;
constexpr float PI_F = 3.14159265358979323846f;
constexpr float HALF_PI_F = 1.57079632679489661923f;
constexpr float INV_TWO_PI_F = 0.15915494309189533577f;

// wrap count: k = floor((d+pi)/(2pi)), with the reference's dm==-pi & d>0 fixup.
__device__ __forceinline__ int wrap_k(float d) {
    float kf = floorf(__fmaf_rn(d, INV_TWO_PI_F, 0.5f));
    float dm = __fmaf_rn(-kf, TWO_PI_F, d);
    if (dm == -PI_F && d > 0.f) kf -= 1.f;
    return (int)kf;
}

// polynomial atan2, abs err ~2e-7 rad
__device__ __forceinline__ float fast_atan2f(float q, float i) {
    float aq = fabsf(q), ai = fabsf(i);
    float mx = fmaxf(aq, ai), mn = fminf(aq, ai);
    float r = __builtin_amdgcn_rcpf(mx);
    r = r * (2.0f - mx * r);                 // one NR step
    float t = mn * r;                        // in [0, 1+eps]
    if (mx == 0.f) t = 0.f;                  // atan2(0,0) -> 0
    float s = t * t;
    float p = __fmaf_rn(s, 0.0028662257f, -0.0161657367f);
    p = __fmaf_rn(p, s,  0.0429096138f);
    p = __fmaf_rn(p, s, -0.0752896400f);
    p = __fmaf_rn(p, s,  0.1065626393f);
    p = __fmaf_rn(p, s, -0.1420889944f);
    p = __fmaf_rn(p, s,  0.1999355085f);
    p = __fmaf_rn(p, s, -0.3333314528f);
    float at = __fmaf_rn(p * s, t, t);       // t + t*s*poly
    if (aq > ai) at = HALF_PI_F - at;
    if (i < 0.f) at = PI_F - at;
    return (q < 0.f) ? -at : at;
}

// direct global->LDS DMA, 16 bytes per lane; lds_base must be wave-uniform
__device__ __forceinline__ void gload_lds16(const float* g, float* lds_base) {
    __builtin_amdgcn_global_load_lds(
        (__attribute__((address_space(1))) void*)(uintptr_t)(const void*)g,
        (__attribute__((address_space(3))) void*)(uintptr_t)(void*)lds_base,
        16, 0, 0);
}

// K1: locally-anchored unwrap + moving-average high-pass.
// Raw element li lives at slot li+1 (DMA'd); prefix P[li]/M[li] overwrite at
// slot li. Thread t owns li in [12t, 12t+12); all LDS access is b64/b128.
__global__ __launch_bounds__(TPB, 6) void k_filt(const float* __restrict__ Ig,
                                                 const float* __restrict__ Qg,
                                                 int* __restrict__ Ag,     // local scan at g=t0-1
                                                 int* __restrict__ Bg,     // local scan at g=t0+S-1
                                                 float* __restrict__ out,
                                                 float* __restrict__ PS) {
    __shared__ __align__(16) float sI_s[LDSZ];    // raw I -> prefix(pu)
    __shared__ __align__(16) float sQ_s[LDSZ];    // raw Q -> prefix(magnitude)
    __shared__ int iwt[NW];
    __shared__ float fwt[NW];
    __shared__ float fwt2[NW];
    __shared__ float rbuf[NW][4];

    const int c = blockIdx.x, b = blockIdx.y;
    const int t0 = c * S;
    const int base = t0 - 151;
    const int astart = base - 1;        // slot 0 <-> g = astart (16B-aligned)
    const int tid = threadIdx.x;
    const int lane = tid & 63, wid = tid >> 6;
    const bool edge = (c == 0) | (c == NC - 1);
    const float* Ib = Ig + (size_t)b * Ln;
    const float* Qb = Qg + (size_t)b * Ln;

    if (!edge) {
        const float* gI = Ib + astart;
        const float* gQ = Qb + astart;
#pragma unroll
        for (int k = wid; k < 11; k += NW) {
            int f = k * 64 + lane;
            if (f < NF4) {
                gload_lds16(gI + 4 * f, sI_s + k * 256);
                gload_lds16(gQ + 4 * f, sQ_s + k * 256);
            }
        }
    } else {
        // edge chunks: guarded scalar staging of raw I/Q, slots [0,2560)
#pragma unroll
        for (int j = 0; j < 10; ++j) {
            int k = tid + j * TPB;
            int g = astart + k;
            float a = 0.f, q = 0.f;
            if (g >= 0 && g < Ln) { a = Ib[g]; q = Qb[g]; }
            sI_s[k] = a;
            sQ_s[k] = q;
        }
    }
    __syncthreads();                                   // B1 (DMA drained)

    const int s0 = EPT * tid;           // slot of x[0] (li = 12t-1)
    const int gs = astart + s0;         // g of x[0]

    // vector-read own 13 raw elements, convert in registers
    float av[13], qv[13];
    {
        float4 a0 = *reinterpret_cast<const float4*>(sI_s + s0);
        float4 a1 = *reinterpret_cast<const float4*>(sI_s + s0 + 4);
        float4 a2 = *reinterpret_cast<const float4*>(sI_s + s0 + 8);
        float  a3 = sI_s[s0 + 12];
        float4 q0 = *reinterpret_cast<const float4*>(sQ_s + s0);
        float4 q1 = *reinterpret_cast<const float4*>(sQ_s + s0 + 4);
        float4 q2 = *reinterpret_cast<const float4*>(sQ_s + s0 + 8);
        float  q3 = sQ_s[s0 + 12];
        av[0]=a0.x; av[1]=a0.y; av[2]=a0.z; av[3]=a0.w;
        av[4]=a1.x; av[5]=a1.y; av[6]=a1.z; av[7]=a1.w;
        av[8]=a2.x; av[9]=a2.y; av[10]=a2.z; av[11]=a2.w; av[12]=a3;
        qv[0]=q0.x; qv[1]=q0.y; qv[2]=q0.z; qv[3]=q0.w;
        qv[4]=q1.x; qv[5]=q1.y; qv[6]=q1.z; qv[7]=q1.w;
        qv[8]=q2.x; qv[9]=q2.y; qv[10]=q2.z; qv[11]=q2.w; qv[12]=q3;
    }
    float ph[13], mg[13];
#pragma unroll
    for (int i = 0; i < 13; ++i) {
        ph[i] = fast_atan2f(qv[i], av[i]);
        mg[i] = __builtin_amdgcn_sqrtf(__fmaf_rn(av[i], av[i], qv[i] * qv[i]));
    }

    // wrap scan + mg sum (registers only)
    int kloc[13];
    kloc[0] = 0;
    float rm = 0.f;
    {
        int run = 0;
#pragma unroll
        for (int i = 1; i < 13; ++i) {
            run += wrap_k(ph[i] - ph[i - 1]);
            kloc[i] = run;
            rm += mg[i];
        }
    }

    // combined block exclusive scan: int wrap counts + float mg sums
    int vi_ = kloc[12];
    float vf = rm;
#pragma unroll
    for (int o = 1; o < 64; o <<= 1) {
        int ui = __shfl_up(vi_, o, 64);
        float uf = __shfl_up(vf, o, 64);
        if (lane >= o) { vi_ += ui; vf += uf; }
    }
    if (lane == 63) { iwt[wid] = vi_; fwt[wid] = vf; }
    __syncthreads();                                   // B2
    int addi = 0; float addf = 0.f;
#pragma unroll
    for (int w = 0; w < NW; ++w) {
        addi += (w < wid) ? iwt[w] : 0;
        addf += (w < wid) ? fwt[w] : 0.f;
    }
    const int excl = vi_ - kloc[12] + addi;
    const float em = vf - rm + addf;

    if (tid == 12)  Ag[b * NC + c] = excl + kloc[7];   // li=150  (g=t0-1)
    if (tid == 183) Bg[b * NC + c] = excl + kloc[3];   // li=2198 (g=t0+S-1)

    // pu segment sum from registers
    float rp = 0.f;
    if (!edge) {
#pragma unroll
        for (int i = 1; i < 13; ++i)
            rp += __fmaf_rn((float)(excl + kloc[i]), TWO_PI_F, ph[i]);
    } else {
#pragma unroll
        for (int i = 1; i < 13; ++i) {
            int g = gs + i;
            if (g >= 0 && g < Ln)
                rp += __fmaf_rn((float)(excl + kloc[i]), TWO_PI_F, ph[i]);
        }
    }

    // block exclusive scan of pu sums
    float incf = rp;
#pragma unroll
    for (int o = 1; o < 64; o <<= 1) {
        float uf = __shfl_up(incf, o, 64);
        if (lane >= o) incf += uf;
    }
    if (lane == 63) fwt2[wid] = incf;
    __syncthreads();                                   // B3 (raw reads all done)
    float addp = 0.f;
#pragma unroll
    for (int w = 0; w < NW; ++w) addp += (w < wid) ? fwt2[w] : 0.f;
    const float ep = incf - rp + addp;

    // build prefixes in registers, vector-write to slots [12t, 12t+11]
    {
        float P[12], M[12];
        float runp = ep, runm = em;
        if (!edge) {
#pragma unroll
            for (int i = 1; i < 13; ++i) {
                runp += __fmaf_rn((float)(excl + kloc[i]), TWO_PI_F, ph[i]);
                runm += mg[i];
                P[i - 1] = runp;
                M[i - 1] = runm;
            }
        } else {
#pragma unroll
            for (int i = 1; i < 13; ++i) {
                int g = gs + i;
                float v = 0.f;
                if (g >= 0 && g < Ln)
                    v = __fmaf_rn((float)(excl + kloc[i]), TWO_PI_F, ph[i]);
                runp += v;
                runm += mg[i];
                P[i - 1] = runp;
                M[i - 1] = runm;
            }
        }
        *reinterpret_cast<float4*>(sI_s + s0)     = make_float4(P[0], P[1], P[2], P[3]);
        *reinterpret_cast<float4*>(sI_s + s0 + 4) = make_float4(P[4], P[5], P[6], P[7]);
        *reinterpret_cast<float4*>(sI_s + s0 + 8) = make_float4(P[8], P[9], P[10], P[11]);
        *reinterpret_cast<float4*>(sQ_s + s0)     = make_float4(M[0], M[1], M[2], M[3]);
        *reinterpret_cast<float4*>(sQ_s + s0 + 4) = make_float4(M[4], M[5], M[6], M[7]);
        *reinterpret_cast<float4*>(sQ_s + s0 + 8) = make_float4(M[8], M[9], M[10], M[11]);
    }
    __syncthreads();                                   // B4

    // output: 2 groups of 4 consecutive outputs; all LDS reads b64/b128
    float s1mf = 0.f, s2mf = 0.f, s1pf = 0.f, s2pf = 0.f;
    float* om = out + ((size_t)b * 2) * Ln + t0;
    float* op = out + ((size_t)b * 2 + 1) * Ln + t0;
    constexpr float INV_K = 1.0f / 301.0f;
#pragma unroll
    for (int g2 = 0; g2 < 2; ++g2) {
        const int t = 4 * tid + (g2 << 10);
        float4 P0 = *reinterpret_cast<const float4*>(sI_s + t);        // P[t..t+3]
        float2 Pa = *reinterpret_cast<const float2*>(sI_s + t + 150);  // P[t+150,151]
        float4 Pb = *reinterpret_cast<const float4*>(sI_s + t + 152);  // P[t+152..155]
        float4 Pc = *reinterpret_cast<const float4*>(sI_s + t + 300);  // P[t+300..303]
        float  Pd = sI_s[t + 304];
        float4 M0 = *reinterpret_cast<const float4*>(sQ_s + t);
        float2 Ma = *reinterpret_cast<const float2*>(sQ_s + t + 150);
        float4 Mb = *reinterpret_cast<const float4*>(sQ_s + t + 152);
        float4 Mc = *reinterpret_cast<const float4*>(sQ_s + t + 300);
        float  Md = sQ_s[t + 304];

        float4 fmv, fpv;
        fmv.x = (Ma.y - Ma.x) - (Mc.y - M0.x) * INV_K;
        fmv.y = (Mb.x - Ma.y) - (Mc.z - M0.y) * INV_K;
        fmv.z = (Mb.y - Mb.x) - (Mc.w - M0.z) * INV_K;
        fmv.w = (Mb.z - Mb.y) - (Md   - M0.w) * INV_K;
        fpv.x = (Pa.y - Pa.x) - (Pc.y - P0.x) * INV_K;
        fpv.y = (Pb.x - Pa.y) - (Pc.z - P0.y) * INV_K;
        fpv.z = (Pb.y - Pb.x) - (Pc.w - P0.z) * INV_K;
        fpv.w = (Pb.z - Pb.y) - (Pd   - P0.w) * INV_K;

        *reinterpret_cast<float4*>(om + t) = fmv;
        *reinterpret_cast<float4*>(op + t) = fpv;

        s1mf += fmv.x + fmv.y + fmv.z + fmv.w;
        s2mf = __fmaf_rn(fmv.x, fmv.x, s2mf); s2mf = __fmaf_rn(fmv.y, fmv.y, s2mf);
        s2mf = __fmaf_rn(fmv.z, fmv.z, s2mf); s2mf = __fmaf_rn(fmv.w, fmv.w, s2mf);
        s1pf += fpv.x + fpv.y + fpv.z + fpv.w;
        s2pf = __fmaf_rn(fpv.x, fpv.x, s2pf); s2pf = __fmaf_rn(fpv.y, fpv.y, s2pf);
        s2pf = __fmaf_rn(fpv.z, fpv.z, s2pf); s2pf = __fmaf_rn(fpv.w, fpv.w, s2pf);
    }
    // f32 wave reduce
#pragma unroll
    for (int o = 32; o > 0; o >>= 1) {
        s1mf += __shfl_down(s1mf, o, 64);
        s2mf += __shfl_down(s2mf, o, 64);
        s1pf += __shfl_down(s1pf, o, 64);
        s2pf += __shfl_down(s2pf, o, 64);
    }
    if (lane == 0) { rbuf[wid][0] = s1mf; rbuf[wid][1] = s2mf; rbuf[wid][2] = s1pf; rbuf[wid][3] = s2pf; }
    __syncthreads();                                   // B5
    if (tid == 0) {
        float t0f = 0.f, t1f = 0.f, t2f = 0.f, t3f = 0.f;
#pragma unroll
        for (int w = 0; w < NW; ++w) {
            t0f += rbuf[w][0]; t1f += rbuf[w][1]; t2f += rbuf[w][2]; t3f += rbuf[w][3];
        }
        float* p = PS + (size_t)(b * NC + c) * 4;
        p[0] = t0f; p[1] = t1f; p[2] = t2f; p[3] = t3f;
    }
}

// K2: per-row: fix last-150 phase outputs (right-pad windows) + row stats.
__global__ void k_post(const int* __restrict__ Ag, const int* __restrict__ Bg,
                       float* __restrict__ out, const float* __restrict__ PS,
                       float* __restrict__ ROW) {
    const int b = blockIdx.x;
    const int lane = threadIdx.x;           // 64 threads
    const int idx = b * NC;

    // row wrap offset at chunk NC-1 start: sum W_c over c<NC-1
    int w = (Bg[idx + lane] - Ag[idx + lane]);
    if (lane + 64 < NC - 1) w += (Bg[idx + 64 + lane] - Ag[idx + 64 + lane]);
#pragma unroll
    for (int o = 32; o > 0; o >>= 1) w += __shfl_down(w, o, 64);
    int O = __shfl(w, 0, 64);
    int aL = Ag[idx + NC - 1];
    float C = TWO_PI_F * (float)(O - aL);   // pu_true - pu_prov for last chunk

    constexpr float INV_K = 1.0f / 301.0f;
    float* op = out + ((size_t)b * 2 + 1) * Ln;
    double sd = 0.0, sd2 = 0.0;
#pragma unroll
    for (int k = 0; k < 3; ++k) {
        int j = lane + k * 64;
        if (j < 150) {
            int t = Ln - 150 + j;           // npad in window = j+1
            float delta = C * (float)(j + 1) * INV_K;
            float v = op[t];
            float nv = v + delta;
            op[t] = nv;
            sd += (double)delta;
            sd2 += (double)nv * (double)nv - (double)v * (double)v;
        }
    }

    // row stats: each lane sums 2 chunks, plus its own fix deltas
    const float* p1 = PS + (size_t)(idx + lane) * 4;
    const float* p2 = PS + (size_t)(idx + 64 + lane) * 4;
    double a0 = (double)p1[0] + (double)p2[0];
    double a1 = (double)p1[1] + (double)p2[1];
    double a2 = (double)p1[2] + (double)p2[2] + sd;
    double a3 = (double)p1[3] + (double)p2[3] + sd2;
#pragma unroll
    for (int o = 32; o > 0; o >>= 1) {
        a0 += __shfl_down(a0, o, 64);
        a1 += __shfl_down(a1, o, 64);
        a2 += __shfl_down(a2, o, 64);
        a3 += __shfl_down(a3, o, 64);
    }
    if (lane == 0) {
        double Ld = (double)Ln;
        double mm = a0 / Ld;
        double vm = (a1 - a0 * a0 / Ld) / (Ld - 1.0); vm = vm > 0 ? vm : 0;
        double mp = a2 / Ld;
        double vp = (a3 - a2 * a2 / Ld) / (Ld - 1.0); vp = vp > 0 ? vp : 0;
        float* r = ROW + b * 4;
        r[0] = (float)mm;
        r[1] = (float)(1.0 / (sqrt(vm) + 1e-5));
        r[2] = (float)mp;
        r[3] = (float)(1.0 / (sqrt(vp) + 1e-5));
    }
}

// in-place normalize of d_out
__global__ __launch_bounds__(256) void k_norm(float* __restrict__ out,
                                              const float* __restrict__ ROW) {
    const size_t n4 = (size_t)Bn * 2 * Ln / 4;
    size_t stride = (size_t)gridDim.x * blockDim.x;
    for (size_t p4 = (size_t)blockIdx.x * blockDim.x + threadIdx.x; p4 < n4; p4 += stride) {
        size_t p = p4 * 4;
        int b = (int)(p >> 19);             // 2L = 2^19
        int sig = (int)((p >> 18) & 1);     // L = 2^18
        float mean = ROW[b * 4 + sig * 2];
        float scale = ROW[b * 4 + sig * 2 + 1];
        float4 v = reinterpret_cast<float4*>(out)[p4];
        v.x = (v.x - mean) * scale;
        v.y = (v.y - mean) * scale;
        v.z = (v.z - mean) * scale;
        v.w = (v.w - mean) * scale;
        reinterpret_cast<float4*>(out)[p4] = v;
    }
}

extern "C" void kernel_launch(void* const* d_in, const int* in_sizes, int n_in,
                              void* d_out, int out_size, void* d_ws, size_t ws_size,
                              hipStream_t stream) {
    const float* Ig = (const float*)d_in[0];
    const float* Qg = (const float*)d_in[1];
    float* out = (float*)d_out;
    char* ws = (char*)d_ws;
    int* Ag = (int*)ws;                                 // Bn*NC ints (32 KiB)
    int* Bg = (int*)(ws + 32768);                       // Bn*NC ints (32 KiB)
    float* PS = (float*)(ws + 65536);                   // Bn*NC*4 floats (128 KiB)
    float* ROW = (float*)(ws + 65536 + (size_t)Bn * NC * 4 * sizeof(float));

    dim3 grid(NC, Bn);
    hipLaunchKernelGGL(k_filt, grid, dim3(TPB), 0, stream, Ig, Qg, Ag, Bg, out, PS);
    hipLaunchKernelGGL(k_post, dim3(Bn), dim3(64), 0, stream, Ag, Bg, out, PS, ROW);
    hipLaunchKernelGGL(k_norm, dim3(4096), dim3(256), 0, stream, out, ROW);
}

// Round 18
// 98.871 us; speedup vs baseline: 1.1121x; 1.1121x over previous
//
#include <hip/hip_runtime.h>
#include <math.h>
#include <stdint.h>

#define TPB 256
constexpr int Bn = 64;
constexpr int Ln = 262144;          // 2^18
constexpr int S  = 2048;            // chunk/tile size
constexpr int NC = Ln / S;          // 128 chunks per row
constexpr int HA = S + 301;         // halo'd extent (2349)
constexpr int EPT = 11;             // segment length; ODD stride -> conflict-free LDS
constexpr int OPT = S / TPB;        // 8 outputs per thread
constexpr int RAWMAX = 2355;        // last DEFINED raw slot (max read = 2354)
constexpr int NF4 = 589;            // float4s DMA'd per array (raw slots [0,2356))
constexpr int LDSZ = 2360;          // slots; last raw 2355, last prefix write 2354
constexpr int TMAX = 214;           // threads with live segments (11*213+11 = 2354)
constexpr int NW = TPB / 64;

constexpr float TWO_PI_F = 6.28318530717958647692f;
constexpr float PI_F = 3.14159265358979323846f;
constexpr float HALF_PI_F = 1.57079632679489661923f;
constexpr float INV_TWO_PI_F = 0.15915494309189533577f;

// wrap count: k = floor((d+pi)/(2pi)), with the reference's dm==-pi & d>0 fixup.
__device__ __forceinline__ int wrap_k(float d) {
    float kf = floorf(__fmaf_rn(d, INV_TWO_PI_F, 0.5f));
    float dm = __fmaf_rn(-kf, TWO_PI_F, d);
    if (dm == -PI_F && d > 0.f) kf -= 1.f;
    return (int)kf;
}

// polynomial atan2, abs err ~2e-7 rad
__device__ __forceinline__ float fast_atan2f(float q, float i) {
    float aq = fabsf(q), ai = fabsf(i);
    float mx = fmaxf(aq, ai), mn = fminf(aq, ai);
    float r = __builtin_amdgcn_rcpf(mx);
    r = r * (2.0f - mx * r);                 // one NR step
    float t = mn * r;                        // in [0, 1+eps]
    if (mx == 0.f) t = 0.f;                  // atan2(0,0) -> 0
    float s = t * t;
    float p = __fmaf_rn(s, 0.0028662257f, -0.0161657367f);
    p = __fmaf_rn(p, s,  0.0429096138f);
    p = __fmaf_rn(p, s, -0.0752896400f);
    p = __fmaf_rn(p, s,  0.1065626393f);
    p = __fmaf_rn(p, s, -0.1420889944f);
    p = __fmaf_rn(p, s,  0.1999355085f);
    p = __fmaf_rn(p, s, -0.3333314528f);
    float at = __fmaf_rn(p * s, t, t);       // t + t*s*poly
    if (aq > ai) at = HALF_PI_F - at;
    if (i < 0.f) at = PI_F - at;
    return (q < 0.f) ? -at : at;
}

// direct global->LDS DMA, 16 bytes per lane; lds_base must be wave-uniform
__device__ __forceinline__ void gload_lds16(const float* g, float* lds_base) {
    __builtin_amdgcn_global_load_lds(
        (__attribute__((address_space(1))) void*)(uintptr_t)(const void*)g,
        (__attribute__((address_space(3))) void*)(uintptr_t)(void*)lds_base,
        16, 0, 0);
}

// K1: locally-anchored unwrap + moving-average high-pass. DMA stages raw I/Q
// into LDS; threads convert their stride-11 segments in registers; the same
// LDS buffers are overwritten with the two inclusive-prefix arrays.
// Slot k holds raw element li = k-1; prefix P[li]/M[li] at slot li+1.
// Coverage invariant: every raw slot that ANY thread reads (<= RAWMAX) is
// written every call -> kernel is a pure function of d_in (replay-safe).
__global__ __launch_bounds__(TPB, 8) void k_filt(const float* __restrict__ Ig,
                                                 const float* __restrict__ Qg,
                                                 int* __restrict__ Ag,     // local scan at g=t0-1
                                                 int* __restrict__ Bg,     // local scan at g=t0+S-1
                                                 float* __restrict__ out,
                                                 float* __restrict__ PS) {
    __shared__ __align__(16) float sI_s[LDSZ];    // raw I -> prefix(pu)
    __shared__ __align__(16) float sQ_s[LDSZ];    // raw Q -> prefix(magnitude)
    __shared__ int iwt[NW];
    __shared__ float fwt[NW];
    __shared__ float fwt2[NW];
    __shared__ float rbuf[NW][4];
    float* spu = sI_s + 1;              // prefix(pu)[li]  at slot li+1
    float* smg = sQ_s + 1;              // prefix(mg)[li]  at slot li+1

    const int c = blockIdx.x, b = blockIdx.y;
    const int t0 = c * S;
    const int base = t0 - 151;
    const int astart = base - 1;        // slot 0 <-> g = astart (16B-aligned)
    const int tid = threadIdx.x;
    const int lane = tid & 63, wid = tid >> 6;
    const bool edge = (c == 0) | (c == NC - 1);
    const bool live = tid < TMAX;
    const float* Ib = Ig + (size_t)b * Ln;
    const float* Qb = Qg + (size_t)b * Ln;

    if (!edge) {
        const float* gI = Ib + astart;
        const float* gQ = Qb + astart;
#pragma unroll
        for (int k = wid; k < 10; k += NW) {
            int f = k * 64 + lane;
            if (f < NF4) {
                gload_lds16(gI + 4 * f, sI_s + k * 256);
                gload_lds16(gQ + 4 * f, sQ_s + k * 256);
            }
        }
    } else {
        // edge chunks: guarded scalar staging of raw I/Q, slots [0, RAWMAX]
#pragma unroll
        for (int j = 0; j < 10; ++j) {
            int k = tid + j * TPB;
            if (k <= RAWMAX) {
                int g = astart + k;
                float a = 0.f, q = 0.f;
                if (g >= 0 && g < Ln) { a = Ib[g]; q = Qb[g]; }
                sI_s[k] = a;
                sQ_s[k] = q;
            }
        }
    }
    __syncthreads();                                   // B1 (DMA drained)

    const int kb = EPT * tid;           // slot of x[0] (li = 11t-1)
    const int gs = astart + kb;         // g of x[0]

    // convert own 12 elements from LDS raw -> registers.
    // Clamped index: every read slot is DEFINED (deterministic across calls);
    // dead threads' (tid>=TMAX) values are quarantined (no prefix writes, and
    // their scan contributions reach only other dead threads).
    float ph[12], mg[12];
#pragma unroll
    for (int i = 0; i < 12; ++i) {
        int ks = kb + i;
        ks = ks > RAWMAX ? RAWMAX : ks;
        float a = sI_s[ks], q = sQ_s[ks];
        ph[i] = fast_atan2f(q, a);      // (0,0) -> 0
        mg[i] = __builtin_amdgcn_sqrtf(__fmaf_rn(a, a, q * q));
    }

    // wrap scan + mg sum (registers only)
    int kloc[12];
    kloc[0] = 0;
    float rm = 0.f;
    {
        int run = 0;
#pragma unroll
        for (int i = 1; i < 12; ++i) {
            run += wrap_k(ph[i] - ph[i - 1]);
            kloc[i] = run;
            rm += mg[i];
        }
    }

    // combined block exclusive scan: int wrap counts + float mg sums
    int vi_ = kloc[11];
    float vf = rm;
#pragma unroll
    for (int o = 1; o < 64; o <<= 1) {
        int ui = __shfl_up(vi_, o, 64);
        float uf = __shfl_up(vf, o, 64);
        if (lane >= o) { vi_ += ui; vf += uf; }
    }
    if (lane == 63) { iwt[wid] = vi_; fwt[wid] = vf; }
    __syncthreads();                                   // B2
    int addi = 0; float addf = 0.f;
#pragma unroll
    for (int w = 0; w < NW; ++w) {
        addi += (w < wid) ? iwt[w] : 0;
        addf += (w < wid) ? fwt[w] : 0.f;
    }
    const int excl = vi_ - kloc[11] + addi;
    const float em = vf - rm + addf;

    if (tid == 13)  Ag[b * NC + c] = excl + kloc[8];   // scan at li=150  (g=t0-1)
    if (tid == 199) Bg[b * NC + c] = excl + kloc[10];  // scan at li=2198 (g=t0+S-1)

    // pu segment sum from registers
    float rp = 0.f;
    if (!edge) {
#pragma unroll
        for (int i = 1; i < 12; ++i)
            rp += __fmaf_rn((float)(excl + kloc[i]), TWO_PI_F, ph[i]);
    } else {
#pragma unroll
        for (int i = 1; i < 12; ++i) {
            int g = gs + i;
            if (g >= 0 && g < Ln)
                rp += __fmaf_rn((float)(excl + kloc[i]), TWO_PI_F, ph[i]);
        }
    }

    // block exclusive scan of pu sums
    float incf = rp;
#pragma unroll
    for (int o = 1; o < 64; o <<= 1) {
        float uf = __shfl_up(incf, o, 64);
        if (lane >= o) incf += uf;
    }
    if (lane == 63) fwt2[wid] = incf;
    __syncthreads();                                   // B3 (raw reads all done)
    float addp = 0.f;
#pragma unroll
    for (int w = 0; w < NW; ++w) addp += (w < wid) ? fwt2[w] : 0.f;
    const float ep = incf - rp + addp;

    // overwrite LDS with inclusive prefixes from registers (stride-11,
    // conflict-free, write-only). Dead threads write nothing.
    if (live) {
        if (!edge) {
            float runp = ep, runm = em;
#pragma unroll
            for (int i = 1; i < 12; ++i) {
                int li = kb + i - 1;
                runp += __fmaf_rn((float)(excl + kloc[i]), TWO_PI_F, ph[i]);
                spu[li] = runp;
                runm += mg[i];
                smg[li] = runm;
            }
        } else {
            float runp = ep, runm = em;
#pragma unroll
            for (int i = 1; i < 12; ++i) {
                int li = kb + i - 1;
                int g = gs + i;
                float v = 0.f;
                if (g >= 0 && g < Ln)
                    v = __fmaf_rn((float)(excl + kloc[i]), TWO_PI_F, ph[i]);
                runp += v;
                spu[li] = runp;
                runm += mg[i];
                smg[li] = runm;
            }
        }
    }
    __syncthreads();                                   // B4

    float s1mf = 0.f, s2mf = 0.f, s1pf = 0.f, s2pf = 0.f;
    float* om = out + ((size_t)b * 2) * Ln + t0;
    float* op = out + ((size_t)b * 2 + 1) * Ln + t0;
    constexpr float INV_K = 1.0f / 301.0f;
#pragma unroll
    for (int j = 0; j < OPT; ++j) {
        int t = tid + j * TPB;
        int lt = t + 151;
        float Mq = smg[lt - 151], Mm = smg[lt - 1], Ml = smg[lt], Mp = smg[lt + 150];
        float Pq = spu[lt - 151], Pm = spu[lt - 1], Pl = spu[lt], Pp = spu[lt + 150];
        float fm = (Ml - Mm) - (Mp - Mq) * INV_K;
        float fp = (Pl - Pm) - (Pp - Pq) * INV_K;
        om[t] = fm;
        op[t] = fp;
        s1mf += fm; s2mf = __fmaf_rn(fm, fm, s2mf);
        s1pf += fp; s2pf = __fmaf_rn(fp, fp, s2pf);
    }
    // f32 wave reduce
#pragma unroll
    for (int o = 32; o > 0; o >>= 1) {
        s1mf += __shfl_down(s1mf, o, 64);
        s2mf += __shfl_down(s2mf, o, 64);
        s1pf += __shfl_down(s1pf, o, 64);
        s2pf += __shfl_down(s2pf, o, 64);
    }
    if (lane == 0) { rbuf[wid][0] = s1mf; rbuf[wid][1] = s2mf; rbuf[wid][2] = s1pf; rbuf[wid][3] = s2pf; }
    __syncthreads();                                   // B5
    if (tid == 0) {
        float t0f = 0.f, t1f = 0.f, t2f = 0.f, t3f = 0.f;
#pragma unroll
        for (int w = 0; w < NW; ++w) {
            t0f += rbuf[w][0]; t1f += rbuf[w][1]; t2f += rbuf[w][2]; t3f += rbuf[w][3];
        }
        float* p = PS + (size_t)(b * NC + c) * 4;
        p[0] = t0f; p[1] = t1f; p[2] = t2f; p[3] = t3f;
    }
}

// K2: per-row: fix last-150 phase outputs (right-pad windows) + row stats.
// One wave per row (NC==128: two chunks per lane).
__global__ void k_post(const int* __restrict__ Ag, const int* __restrict__ Bg,
                       float* __restrict__ out, const float* __restrict__ PS,
                       float* __restrict__ ROW) {
    const int b = blockIdx.x;
    const int lane = threadIdx.x;           // 64 threads
    const int idx = b * NC;

    // row wrap offset at chunk NC-1 start: sum W_c over c<NC-1
    int w = (Bg[idx + lane] - Ag[idx + lane]);
    if (lane + 64 < NC - 1) w += (Bg[idx + 64 + lane] - Ag[idx + 64 + lane]);
#pragma unroll
    for (int o = 32; o > 0; o >>= 1) w += __shfl_down(w, o, 64);
    int O = __shfl(w, 0, 64);
    int aL = Ag[idx + NC - 1];
    float C = TWO_PI_F * (float)(O - aL);   // pu_true - pu_prov for last chunk

    constexpr float INV_K = 1.0f / 301.0f;
    float* op = out + ((size_t)b * 2 + 1) * Ln;
    double sd = 0.0, sd2 = 0.0;
#pragma unroll
    for (int k = 0; k < 3; ++k) {
        int j = lane + k * 64;
        if (j < 150) {
            int t = Ln - 150 + j;           // npad in window = j+1
            float delta = C * (float)(j + 1) * INV_K;
            float v = op[t];
            float nv = v + delta;
            op[t] = nv;
            sd += (double)delta;
            sd2 += (double)nv * (double)nv - (double)v * (double)v;
        }
    }

    // row stats: each lane sums 2 chunks, plus its own fix deltas
    const float* p1 = PS + (size_t)(idx + lane) * 4;
    const float* p2 = PS + (size_t)(idx + 64 + lane) * 4;
    double a0 = (double)p1[0] + (double)p2[0];
    double a1 = (double)p1[1] + (double)p2[1];
    double a2 = (double)p1[2] + (double)p2[2] + sd;
    double a3 = (double)p1[3] + (double)p2[3] + sd2;
#pragma unroll
    for (int o = 32; o > 0; o >>= 1) {
        a0 += __shfl_down(a0, o, 64);
        a1 += __shfl_down(a1, o, 64);
        a2 += __shfl_down(a2, o, 64);
        a3 += __shfl_down(a3, o, 64);
    }
    if (lane == 0) {
        double Ld = (double)Ln;
        double mm = a0 / Ld;
        double vm = (a1 - a0 * a0 / Ld) / (Ld - 1.0); vm = vm > 0 ? vm : 0;
        double mp = a2 / Ld;
        double vp = (a3 - a2 * a2 / Ld) / (Ld - 1.0); vp = vp > 0 ? vp : 0;
        float* r = ROW + b * 4;
        r[0] = (float)mm;
        r[1] = (float)(1.0 / (sqrt(vm) + 1e-5));
        r[2] = (float)mp;
        r[3] = (float)(1.0 / (sqrt(vp) + 1e-5));
    }
}

// in-place normalize of d_out
__global__ __launch_bounds__(256) void k_norm(float* __restrict__ out,
                                              const float* __restrict__ ROW) {
    const size_t n4 = (size_t)Bn * 2 * Ln / 4;
    size_t stride = (size_t)gridDim.x * blockDim.x;
    for (size_t p4 = (size_t)blockIdx.x * blockDim.x + threadIdx.x; p4 < n4; p4 += stride) {
        size_t p = p4 * 4;
        int b = (int)(p >> 19);             // 2L = 2^19
        int sig = (int)((p >> 18) & 1);     // L = 2^18
        float mean = ROW[b * 4 + sig * 2];
        float scale = ROW[b * 4 + sig * 2 + 1];
        float4 v = reinterpret_cast<float4*>(out)[p4];
        v.x = (v.x - mean) * scale;
        v.y = (v.y - mean) * scale;
        v.z = (v.z - mean) * scale;
        v.w = (v.w - mean) * scale;
        reinterpret_cast<float4*>(out)[p4] = v;
    }
}

extern "C" void kernel_launch(void* const* d_in, const int* in_sizes, int n_in,
                              void* d_out, int out_size, void* d_ws, size_t ws_size,
                              hipStream_t stream) {
    const float* Ig = (const float*)d_in[0];
    const float* Qg = (const float*)d_in[1];
    float* out = (float*)d_out;
    char* ws = (char*)d_ws;
    int* Ag = (int*)ws;                                 // Bn*NC ints (32 KiB)
    int* Bg = (int*)(ws + 32768);                       // Bn*NC ints (32 KiB)
    float* PS = (float*)(ws + 65536);                   // Bn*NC*4 floats (128 KiB)
    float* ROW = (float*)(ws + 65536 + (size_t)Bn * NC * 4 * sizeof(float));

    dim3 grid(NC, Bn);
    hipLaunchKernelGGL(k_filt, grid, dim3(TPB), 0, stream, Ig, Qg, Ag, Bg, out, PS);
    hipLaunchKernelGGL(k_post, dim3(Bn), dim3(64), 0, stream, Ag, Bg, out, PS, ROW);
    hipLaunchKernelGGL(k_norm, dim3(4096), dim3(256), 0, stream, out, ROW);
}

// Round 19
// 97.476 us; speedup vs baseline: 1.1280x; 1.0143x over previous
//
#include <hip/hip_runtime.h>
#include <math.h>
#include <stdint.h>

#define TPB 256
constexpr int Bn = 64;
constexpr int Ln = 262144;          // 2^18
constexpr int S  = 2048;            // chunk/tile size
constexpr int NC = Ln / S;          // 128 chunks per row
constexpr int HA = S + 301;         // halo'd extent (2349)
constexpr int EPT = 11;             // segment length; ODD stride -> conflict-free LDS
constexpr int OPT = S / TPB;        // 8 outputs per thread
constexpr int RAWMAX = 2355;        // last DEFINED raw slot (max read = 2354)
constexpr int NF4 = 589;            // float4s DMA'd per array (raw slots [0,2356))
constexpr int LDSZ = 2360;          // slots; last raw 2355, last prefix write 2354
constexpr int TMAX = 214;           // threads with live segments (11*213+11 = 2354)
constexpr int NW = TPB / 64;

constexpr float TWO_PI_F = 6.28318530717958647692f;
constexpr float PI_F = 3.14159265358979323846f;
constexpr float HALF_PI_F = 1.57079632679489661923f;
constexpr float INV_TWO_PI_F = 0.15915494309189533577f;

// wrap count: k = floor((d+pi)/(2pi)), with the reference's dm==-pi & d>0 fixup.
__device__ __forceinline__ int wrap_k(float d) {
    float kf = floorf(__fmaf_rn(d, INV_TWO_PI_F, 0.5f));
    float dm = __fmaf_rn(-kf, TWO_PI_F, d);
    if (dm == -PI_F && d > 0.f) kf -= 1.f;
    return (int)kf;
}

// polynomial atan2, abs err ~2e-7 rad
__device__ __forceinline__ float fast_atan2f(float q, float i) {
    float aq = fabsf(q), ai = fabsf(i);
    float mx = fmaxf(aq, ai), mn = fminf(aq, ai);
    float r = __builtin_amdgcn_rcpf(mx);
    r = r * (2.0f - mx * r);                 // one NR step
    float t = mn * r;                        // in [0, 1+eps]
    if (mx == 0.f) t = 0.f;                  // atan2(0,0) -> 0
    float s = t * t;
    float p = __fmaf_rn(s, 0.0028662257f, -0.0161657367f);
    p = __fmaf_rn(p, s,  0.0429096138f);
    p = __fmaf_rn(p, s, -0.0752896400f);
    p = __fmaf_rn(p, s,  0.1065626393f);
    p = __fmaf_rn(p, s, -0.1420889944f);
    p = __fmaf_rn(p, s,  0.1999355085f);
    p = __fmaf_rn(p, s, -0.3333314528f);
    float at = __fmaf_rn(p * s, t, t);       // t + t*s*poly
    if (aq > ai) at = HALF_PI_F - at;
    if (i < 0.f) at = PI_F - at;
    return (q < 0.f) ? -at : at;
}

// direct global->LDS DMA, 16 bytes per lane; lds_base must be wave-uniform
__device__ __forceinline__ void gload_lds16(const float* g, float* lds_base) {
    __builtin_amdgcn_global_load_lds(
        (__attribute__((address_space(1))) void*)(uintptr_t)(const void*)g,
        (__attribute__((address_space(3))) void*)(uintptr_t)(void*)lds_base,
        16, 0, 0);
}

// K1: locally-anchored unwrap + moving-average high-pass. DMA stages raw I/Q
// into LDS; threads convert their stride-11 segments in registers; the same
// LDS buffers are overwritten with the two inclusive-prefix arrays.
// Slot k holds raw element li = k-1; prefix P[li]/M[li] at slot li+1.
// Stats stored PER-WAVE (no final block reduce); k_post sums the 4 waves.
__global__ __launch_bounds__(TPB, 8) void k_filt(const float* __restrict__ Ig,
                                                 const float* __restrict__ Qg,
                                                 int* __restrict__ Ag,     // local scan at g=t0-1
                                                 int* __restrict__ Bg,     // local scan at g=t0+S-1
                                                 float* __restrict__ out,
                                                 float* __restrict__ PS) {
    __shared__ __align__(16) float sI_s[LDSZ];    // raw I -> prefix(pu)
    __shared__ __align__(16) float sQ_s[LDSZ];    // raw Q -> prefix(magnitude)
    __shared__ int iwt[NW];
    __shared__ float fwt[NW];
    __shared__ float fwt2[NW];
    float* spu = sI_s + 1;              // prefix(pu)[li]  at slot li+1
    float* smg = sQ_s + 1;              // prefix(mg)[li]  at slot li+1

    const int c = blockIdx.x, b = blockIdx.y;
    const int t0 = c * S;
    const int base = t0 - 151;
    const int astart = base - 1;        // slot 0 <-> g = astart (16B-aligned)
    const int tid = threadIdx.x;
    const int lane = tid & 63, wid = tid >> 6;
    const bool edge = (c == 0) | (c == NC - 1);
    const bool live = tid < TMAX;
    const float* Ib = Ig + (size_t)b * Ln;
    const float* Qb = Qg + (size_t)b * Ln;

    if (!edge) {
        const float* gI = Ib + astart;
        const float* gQ = Qb + astart;
#pragma unroll
        for (int k = wid; k < 10; k += NW) {
            int f = k * 64 + lane;
            if (f < NF4) {
                gload_lds16(gI + 4 * f, sI_s + k * 256);
                gload_lds16(gQ + 4 * f, sQ_s + k * 256);
            }
        }
    } else {
        // edge chunks: guarded scalar staging of raw I/Q, slots [0, RAWMAX]
#pragma unroll
        for (int j = 0; j < 10; ++j) {
            int k = tid + j * TPB;
            if (k <= RAWMAX) {
                int g = astart + k;
                float a = 0.f, q = 0.f;
                if (g >= 0 && g < Ln) { a = Ib[g]; q = Qb[g]; }
                sI_s[k] = a;
                sQ_s[k] = q;
            }
        }
    }
    __syncthreads();                                   // B1 (DMA drained)

    const int kb = EPT * tid;           // slot of x[0] (li = 11t-1)

    // convert own 12 elements from LDS raw -> registers (clamped index:
    // every read slot is DEFINED -> deterministic across calls)
    float ph[12], mg[12];
#pragma unroll
    for (int i = 0; i < 12; ++i) {
        int ks = kb + i;
        ks = ks > RAWMAX ? RAWMAX : ks;
        float a = sI_s[ks], q = sQ_s[ks];
        ph[i] = fast_atan2f(q, a);      // (0,0) -> 0
        mg[i] = __builtin_amdgcn_sqrtf(__fmaf_rn(a, a, q * q));
    }

    // wrap scan + mg sum (registers only)
    int kloc[12];
    kloc[0] = 0;
    float rm = 0.f;
    {
        int run = 0;
#pragma unroll
        for (int i = 1; i < 12; ++i) {
            run += wrap_k(ph[i] - ph[i - 1]);
            kloc[i] = run;
            rm += mg[i];
        }
    }

    // combined block exclusive scan: int wrap counts + float mg sums
    int vi_ = kloc[11];
    float vf = rm;
#pragma unroll
    for (int o = 1; o < 64; o <<= 1) {
        int ui = __shfl_up(vi_, o, 64);
        float uf = __shfl_up(vf, o, 64);
        if (lane >= o) { vi_ += ui; vf += uf; }
    }
    if (lane == 63) { iwt[wid] = vi_; fwt[wid] = vf; }
    __syncthreads();                                   // B2
    int addi = 0; float addf = 0.f;
#pragma unroll
    for (int w = 0; w < NW; ++w) {
        addi += (w < wid) ? iwt[w] : 0;
        addf += (w < wid) ? fwt[w] : 0.f;
    }
    const int excl = vi_ - kloc[11] + addi;
    const float em = vf - rm + addf;

    if (tid == 13)  Ag[b * NC + c] = excl + kloc[8];   // scan at li=150  (g=t0-1)
    if (tid == 199) Bg[b * NC + c] = excl + kloc[10];  // scan at li=2198 (g=t0+S-1)

    // pu values ONCE into registers; segment sum
    float pu[11];
    float rp = 0.f;
    if (!edge) {
#pragma unroll
        for (int i = 1; i < 12; ++i) {
            float v = __fmaf_rn((float)(excl + kloc[i]), TWO_PI_F, ph[i]);
            pu[i - 1] = v;
            rp += v;
        }
    } else {
        const int gs = astart + kb;
#pragma unroll
        for (int i = 1; i < 12; ++i) {
            int g = gs + i;
            float v = 0.f;
            if (g >= 0 && g < Ln)
                v = __fmaf_rn((float)(excl + kloc[i]), TWO_PI_F, ph[i]);
            pu[i - 1] = v;
            rp += v;
        }
    }

    // block exclusive scan of pu sums
    float incf = rp;
#pragma unroll
    for (int o = 1; o < 64; o <<= 1) {
        float uf = __shfl_up(incf, o, 64);
        if (lane >= o) incf += uf;
    }
    if (lane == 63) fwt2[wid] = incf;
    __syncthreads();                                   // B3 (raw reads all done)
    float addp = 0.f;
#pragma unroll
    for (int w = 0; w < NW; ++w) addp += (w < wid) ? fwt2[w] : 0.f;
    const float ep = incf - rp + addp;

    // overwrite LDS with inclusive prefixes from registers (stride-11,
    // conflict-free, write-only). Dead threads write nothing.
    if (live) {
        float runp = ep, runm = em;
#pragma unroll
        for (int i = 0; i < 11; ++i) {
            int li = kb + i;
            runp += pu[i];
            spu[li] = runp;
            runm += mg[i + 1];
            smg[li] = runm;
        }
    }
    __syncthreads();                                   // B4

    float s1mf = 0.f, s2mf = 0.f, s1pf = 0.f, s2pf = 0.f;
    float* om = out + ((size_t)b * 2) * Ln + t0;
    float* op = out + ((size_t)b * 2 + 1) * Ln + t0;
    constexpr float INV_K = 1.0f / 301.0f;
#pragma unroll
    for (int j = 0; j < OPT; ++j) {
        int t = tid + j * TPB;
        int lt = t + 151;
        float Mq = smg[lt - 151], Mm = smg[lt - 1], Ml = smg[lt], Mp = smg[lt + 150];
        float Pq = spu[lt - 151], Pm = spu[lt - 1], Pl = spu[lt], Pp = spu[lt + 150];
        float fm = (Ml - Mm) - (Mp - Mq) * INV_K;
        float fp = (Pl - Pm) - (Pp - Pq) * INV_K;
        om[t] = fm;
        op[t] = fp;
        s1mf += fm; s2mf = __fmaf_rn(fm, fm, s2mf);
        s1pf += fp; s2pf = __fmaf_rn(fp, fp, s2pf);
    }
    // f32 wave reduce; store PER-WAVE partials (no extra barrier)
#pragma unroll
    for (int o = 32; o > 0; o >>= 1) {
        s1mf += __shfl_down(s1mf, o, 64);
        s2mf += __shfl_down(s2mf, o, 64);
        s1pf += __shfl_down(s1pf, o, 64);
        s2pf += __shfl_down(s2pf, o, 64);
    }
    if (lane == 0) {
        float* p = PS + ((size_t)(b * NC + c) * NW + wid) * 4;
        p[0] = s1mf; p[1] = s2mf; p[2] = s1pf; p[3] = s2pf;
    }
}

// K2: per-row: fix last-150 phase outputs (right-pad windows) + row stats.
// One wave per row (NC==128: two chunks per lane; 4 wave-partials each).
__global__ void k_post(const int* __restrict__ Ag, const int* __restrict__ Bg,
                       float* __restrict__ out, const float* __restrict__ PS,
                       float* __restrict__ ROW) {
    const int b = blockIdx.x;
    const int lane = threadIdx.x;           // 64 threads
    const int idx = b * NC;

    // row wrap offset at chunk NC-1 start: sum W_c over c<NC-1
    int w = (Bg[idx + lane] - Ag[idx + lane]);
    if (lane + 64 < NC - 1) w += (Bg[idx + 64 + lane] - Ag[idx + 64 + lane]);
#pragma unroll
    for (int o = 32; o > 0; o >>= 1) w += __shfl_down(w, o, 64);
    int O = __shfl(w, 0, 64);
    int aL = Ag[idx + NC - 1];
    float C = TWO_PI_F * (float)(O - aL);   // pu_true - pu_prov for last chunk

    constexpr float INV_K = 1.0f / 301.0f;
    float* op = out + ((size_t)b * 2 + 1) * Ln;
    double sd = 0.0, sd2 = 0.0;
#pragma unroll
    for (int k = 0; k < 3; ++k) {
        int j = lane + k * 64;
        if (j < 150) {
            int t = Ln - 150 + j;           // npad in window = j+1
            float delta = C * (float)(j + 1) * INV_K;
            float v = op[t];
            float nv = v + delta;
            op[t] = nv;
            sd += (double)delta;
            sd2 += (double)nv * (double)nv - (double)v * (double)v;
        }
    }

    // row stats: each lane sums 2 chunks x 4 wave-partials, plus fix deltas
    double a0 = 0.0, a1 = 0.0, a2 = sd, a3 = sd2;
#pragma unroll
    for (int h = 0; h < 2; ++h) {
        const float* p = PS + ((size_t)(idx + h * 64 + lane) * 4) * 4;
#pragma unroll
        for (int wv = 0; wv < 4; ++wv) {
            a0 += (double)p[4 * wv + 0];
            a1 += (double)p[4 * wv + 1];
            a2 += (double)p[4 * wv + 2];
            a3 += (double)p[4 * wv + 3];
        }
    }
#pragma unroll
    for (int o = 32; o > 0; o >>= 1) {
        a0 += __shfl_down(a0, o, 64);
        a1 += __shfl_down(a1, o, 64);
        a2 += __shfl_down(a2, o, 64);
        a3 += __shfl_down(a3, o, 64);
    }
    if (lane == 0) {
        double Ld = (double)Ln;
        double mm = a0 / Ld;
        double vm = (a1 - a0 * a0 / Ld) / (Ld - 1.0); vm = vm > 0 ? vm : 0;
        double mp = a2 / Ld;
        double vp = (a3 - a2 * a2 / Ld) / (Ld - 1.0); vp = vp > 0 ? vp : 0;
        float* r = ROW + b * 4;
        r[0] = (float)mm;
        r[1] = (float)(1.0 / (sqrt(vm) + 1e-5));
        r[2] = (float)mp;
        r[3] = (float)(1.0 / (sqrt(vp) + 1e-5));
    }
}

// in-place normalize of d_out
__global__ __launch_bounds__(256) void k_norm(float* __restrict__ out,
                                              const float* __restrict__ ROW) {
    const size_t n4 = (size_t)Bn * 2 * Ln / 4;
    size_t stride = (size_t)gridDim.x * blockDim.x;
    for (size_t p4 = (size_t)blockIdx.x * blockDim.x + threadIdx.x; p4 < n4; p4 += stride) {
        size_t p = p4 * 4;
        int b = (int)(p >> 19);             // 2L = 2^19
        int sig = (int)((p >> 18) & 1);     // L = 2^18
        float mean = ROW[b * 4 + sig * 2];
        float scale = ROW[b * 4 + sig * 2 + 1];
        float4 v = reinterpret_cast<float4*>(out)[p4];
        v.x = (v.x - mean) * scale;
        v.y = (v.y - mean) * scale;
        v.z = (v.z - mean) * scale;
        v.w = (v.w - mean) * scale;
        reinterpret_cast<float4*>(out)[p4] = v;
    }
}

extern "C" void kernel_launch(void* const* d_in, const int* in_sizes, int n_in,
                              void* d_out, int out_size, void* d_ws, size_t ws_size,
                              hipStream_t stream) {
    const float* Ig = (const float*)d_in[0];
    const float* Qg = (const float*)d_in[1];
    float* out = (float*)d_out;
    char* ws = (char*)d_ws;
    int* Ag = (int*)ws;                                 // Bn*NC ints (32 KiB)
    int* Bg = (int*)(ws + 32768);                       // Bn*NC ints (32 KiB)
    float* PS = (float*)(ws + 65536);                   // Bn*NC*4waves*4 floats (512 KiB)
    float* ROW = (float*)(ws + 65536 + (size_t)Bn * NC * 16 * sizeof(float));

    dim3 grid(NC, Bn);
    hipLaunchKernelGGL(k_filt, grid, dim3(TPB), 0, stream, Ig, Qg, Ag, Bg, out, PS);
    hipLaunchKernelGGL(k_post, dim3(Bn), dim3(64), 0, stream, Ag, Bg, out, PS, ROW);
    hipLaunchKernelGGL(k_norm, dim3(8192), dim3(256), 0, stream, out, ROW);
}